// Round 4
// baseline (118.560 us; speedup 1.0000x reference)
//
#include <hip/hip_runtime.h>
#include <stdint.h>

// Problem constants (from reference):
//   features: [128, 16384, 6] f32; mask_token: [6] f32; seed 1234
//   MASK_RATIO=0.15 -> target_masked = int(16384*0.15) = 2457
//   n_spans = max(1, int(2457/12.5*2)) = 393
constexpr int NB = 128;
constexpr int SEQ = 16384;
constexpr int NSPANS = 393;
constexpr uint32_t TGT = 2457u;
constexpr int ROWF = SEQ * 6;           // 98304 floats per row
constexpr int ROWF4 = ROWF / 4;         // 24576 float4 per row
constexpr int HALF4 = ROWF4 / 2;        // 12288 float4 per half-row

typedef float f32x4 __attribute__((ext_vector_type(4)));

struct Keys {
  uint32_t klo0, klo1;     // randint(k_len) child-2 key (span=16 pow2: only lower bits matter)
  uint32_t khi_s0, khi_s1; // randint(k_start) child-1 key -> higher bits
  uint32_t klo_s0, klo_s1; // randint(k_start) child-2 key -> lower bits
  uint32_t kn0, kn1;       // k_noise
};

// JAX threefry2x32 (20 rounds)
__host__ __device__ inline void tf2x32(uint32_t k0, uint32_t k1,
                                       uint32_t x0, uint32_t x1,
                                       uint32_t& o0, uint32_t& o1) {
  uint32_t ks[3] = {k0, k1, k0 ^ k1 ^ 0x1BD11BDAu};
  uint32_t a = x0 + ks[0], b = x1 + ks[1];
  const uint32_t rot[2][4] = {{13u,15u,26u,6u},{17u,29u,16u,24u}};
#pragma unroll
  for (int i = 0; i < 5; ++i) {
    const uint32_t* r = rot[i & 1];
#pragma unroll
    for (int j = 0; j < 4; ++j) {
      a += b;
      b = (b << r[j]) | (b >> (32u - r[j]));
      b ^= a;
    }
    a += ks[(i + 1) % 3];
    b += ks[(i + 2) % 3] + (uint32_t)(i + 1);
  }
  o0 = a; o1 = b;
}

// JAX partitionable random_bits (32-bit): bits[j] = a ^ b, (a,b) = tf(key, (0, j))
__device__ inline uint32_t rbits(uint32_t k0, uint32_t k1, uint32_t j) {
  uint32_t o0, o1;
  tf2x32(k0, k1, 0u, j, o0, o1);
  return o0 ^ o1;
}

// Token-select for one float4 at row-relative f4 index qrow. fm bits already
// include validity (folded in phase 5). c0 pattern (e%6): 0 -> all elems pos
// p0 (t0..t3); 2 -> all p0 (t2..t5); 4 -> elems 0,1 = p0 (t4,t5), 2,3 = p0+1
// (t0,t1).
__device__ inline f32x4 tok_select(f32x4 v, int qrow, const uint32_t* fm,
                                   float t0, float t1, float t2,
                                   float t3, float t4, float t5) {
  const int e = qrow * 4;
  const int p0 = e / 6;                 // compiler magic-mul
  const int c0 = e - p0 * 6;            // 0, 2, or 4
  const int p1 = (p0 + 1) & (SEQ - 1); // wrap keeps LDS read in-bounds; m1 unused then
  const uint32_t m0 = (fm[p0 >> 5] >> (p0 & 31)) & 1u;
  const uint32_t m1 = (fm[p1 >> 5] >> (p1 & 31)) & 1u;
  const bool is0 = (c0 == 0), is2 = (c0 == 2);
  const float a0 = is0 ? t0 : (is2 ? t2 : t4);
  const float a1 = is0 ? t1 : (is2 ? t3 : t5);
  const float a2 = is0 ? t2 : (is2 ? t4 : t0);
  const float a3 = is0 ? t3 : (is2 ? t5 : t1);
  const bool u01 = m0 != 0u;
  const bool u23 = (!is0 && !is2) ? (m1 != 0u) : (m0 != 0u);
  v.x = u01 ? a0 : v.x;
  v.y = u01 ? a1 : v.y;
  v.z = u23 ? a2 : v.z;
  v.w = u23 ? a3 : v.w;
  return v;
}

// =============== R11: rowpair + reg-staged reads + phase-5 validity + plain stores ===============
// 256 blocks x 1024 threads (1 block/CU). Block bid: row b = bid>>1, half
// h = bid&1. Both blocks of a row redundantly run maskgen (deterministic ->
// identical fm), each masked-copies its own half-row.
// R4 changes vs R3 (see round journal):
//  - plain stores (nt-store correlated with 0.9 TB/s write trickle in R1-R3;
//    m13's 6.3 TB/s ceiling is plain-store)
//  - ch0-validity folded into phase-5 bit emission (probes hidden under
//    maskgen VALU; copy tail is pure select+store, no dependent global loads)
//  - 8 of 12 float4 reads staged into named registers BEFORE maskgen (drain
//    at first barrier at L3 BW instead of latency-exposed in the tail)
__global__ __launch_bounds__(1024)
void rowpair_kernel(const float* __restrict__ feat, const float* __restrict__ tok,
                    float* __restrict__ out, Keys K) {
  __shared__ uint32_t hist[4096];      // 16 KB
  __shared__ uint32_t cov[SEQ / 32];   // 2 KB
  __shared__ uint32_t fm[SEQ / 32];    // 2 KB
  __shared__ uint32_t wsum[16], ssum[16];
  __shared__ int tielist[256];
  __shared__ uint32_t sH, sA, sT, sN;
  __shared__ int tieCnt;

  const int t = threadIdx.x;
  const int lane = t & 63;
  const int wid = t >> 6;
  const uint32_t bid = blockIdx.x;
  const uint32_t b = bid >> 1;         // row
  const int h = (int)(bid & 1u);       // half

  const size_t rowBase4 = (size_t)b * ROWF4 + (size_t)h * HALF4;
  const f32x4* rf4 = (const f32x4*)feat + rowBase4;
  const float* rowf = feat + (size_t)b * ROWF;   // full-row base (validity probes)

  // ---- issue-early: stage 8 of 12 half-row float4s into named registers ----
  // (rule #20: static names only; consumed after maskgen)
  f32x4 s0 = rf4[t];
  f32x4 s1 = rf4[t + 1024];
  f32x4 s2 = rf4[t + 2048];
  f32x4 s3 = rf4[t + 3072];
  f32x4 s4 = rf4[t + 4096];
  f32x4 s5 = rf4[t + 5120];
  f32x4 s6 = rf4[t + 6144];
  f32x4 s7 = rf4[t + 7168];

  // ---------------- maskgen (R7-validated algorithm) ----------------
  for (int i = t; i < 4096; i += 1024) hist[i] = 0u;
  if (t < SEQ / 32) cov[t] = 0u;
  if (t == 0) tieCnt = 0;
  __syncthreads();

  // ---- phase 1: spans (one thread per span, LDS atomicOr) ----
  if (t < NSPANS) {
    uint32_t j = b * (uint32_t)NSPANS + (uint32_t)t;
    uint32_t lenb = rbits(K.klo0, K.klo1, j);
    uint32_t len = 5u + (lenb & 15u);
    uint32_t hb = rbits(K.khi_s0, K.khi_s1, j);
    uint32_t lb = rbits(K.klo_s0, K.klo_s1, j);
    const uint32_t span = 16379u;       // 2^32 % 16379 = 400
    uint32_t start = ((hb % span) * 400u + (lb % span)) % span;
    uint32_t end = start + len; if (end > (uint32_t)SEQ) end = SEQ;
    uint32_t w0 = start >> 5, w1 = (end - 1u) >> 5;
    for (uint32_t w = w0; w <= w1; ++w) {
      uint32_t bs = (w == w0) ? (start & 31u) : 0u;
      uint32_t be = (w == w1) ? ((end - 1u) & 31u) : 31u;
      uint32_t n = be - bs + 1u;
      uint32_t m = (n >= 32u) ? 0xFFFFFFFFu : (((1u << n) - 1u) << bs);
      atomicOr(&cov[w], m);
    }
  }
  __syncthreads();

  // ---- phase 2: threefry pass -> scores in registers + level-1 hist ----
  const uint32_t jb = b << 14;
  uint32_t sr[16];
#pragma unroll
  for (int i = 0; i < 16; ++i) {
    int s = (i << 10) + t;
    uint32_t bits = rbits(K.kn0, K.kn1, jb + (uint32_t)s);
    uint32_t si = (bits >> 9) + (((cov[s >> 5] >> (s & 31)) & 1u) << 23);
    sr[i] = si;
    atomicAdd(&hist[si >> 12], 1u);
  }
  __syncthreads();

  // ---- phase 3: level-1 select via wave-shuffle suffix scan ----
  {
    uint32_t mysum = 0;
#pragma unroll
    for (int i = 0; i < 4; ++i) mysum += hist[t * 4 + i];
    uint32_t v = mysum;
#pragma unroll
    for (int off = 1; off < 64; off <<= 1) {
      uint32_t n = __shfl_down(v, off, 64);
      if (lane + off < 64) v += n;
    }
    if (lane == 0) wsum[wid] = v;   // wave totals
    __syncthreads();
    if (t < 16) {
      uint32_t w = wsum[t];
#pragma unroll
      for (int off = 1; off < 16; off <<= 1) {
        uint32_t n = __shfl_down(w, off, 64);
        if (t + off < 16) w += n;
      }
      ssum[t] = w;                  // inclusive suffix over wave totals
    }
    __syncthreads();
    uint32_t mine = v + (ssum[wid] - wsum[wid]);   // sum of chunks >= mine
    uint32_t above = mine - mysum;                  // strictly above my chunk
    if (above < TGT && TGT <= mine) {
      uint32_t run = above;
      for (int hb = t * 4 + 3; hb >= t * 4; --hb) {
        uint32_t c = hist[hb];
        if (run + c >= TGT) { sH = (uint32_t)hb; sA = run; break; }
        run += c;
      }
    }
  }
  __syncthreads();
  uint32_t H = sH;
  uint32_t targetB = TGT - sA;

  for (int i = t; i < 4096; i += 1024) hist[i] = 0u;
  __syncthreads();

  // ---- phase 4: level-2 histogram from registers ----
#pragma unroll
  for (int i = 0; i < 16; ++i) {
    uint32_t si = sr[i];
    if ((si >> 12) == H) atomicAdd(&hist[si & 4095u], 1u);
  }
  __syncthreads();
  {
    uint32_t mysum = 0;
#pragma unroll
    for (int i = 0; i < 4; ++i) mysum += hist[t * 4 + i];
    uint32_t v = mysum;
#pragma unroll
    for (int off = 1; off < 64; off <<= 1) {
      uint32_t n = __shfl_down(v, off, 64);
      if (lane + off < 64) v += n;
    }
    if (lane == 0) wsum[wid] = v;
    __syncthreads();
    if (t < 16) {
      uint32_t w = wsum[t];
#pragma unroll
      for (int off = 1; off < 16; off <<= 1) {
        uint32_t n = __shfl_down(w, off, 64);
        if (t + off < 16) w += n;
      }
      ssum[t] = w;
    }
    __syncthreads();
    uint32_t mine = v + (ssum[wid] - wsum[wid]);
    uint32_t above = mine - mysum;
    if (above < targetB && targetB <= mine) {
      uint32_t run = above;
      for (int lb = t * 4 + 3; lb >= t * 4; --lb) {
        uint32_t c = hist[lb];
        if (run + c >= targetB) {
          sT = (H << 12) | (uint32_t)lb;
          sN = targetB - run;   // # ties at T accepted (lowest indices first)
          break;
        }
        run += c;
      }
    }
  }
  __syncthreads();
  uint32_t T = sT, need = sN;

  // ---- phase 5: emit bits (validity folded, probes only for OUR half) ----
  // Reference applies `& valid` AFTER top-k, so tie RANKING ignores validity,
  // but emitted bits are (selected && valid). Our half is exactly iterations
  // i<8 (h==0) or i>=8 (h==1) since s = i*1024 + t.
#pragma unroll
  for (int i = 0; i < 16; ++i) {
    int s = (i << 10) + t;
    uint32_t si = sr[i];
    bool sel = si > T;
    const bool ours = (h == 0) ? (i < 8) : (i >= 8);
    if (ours && sel) {
      float c0v = rowf[(size_t)s * 6];
      sel = !(c0v != c0v);            // valid = !isnan(channel 0)
    }
    unsigned long long bal = __ballot(sel);
    if (si == T) {
      int idx = atomicAdd(&tieCnt, 1);
      if (idx < 256) tielist[idx] = s;
    }
    if (lane == 0)       fm[s >> 5] = (uint32_t)bal;
    else if (lane == 32) fm[s >> 5] = (uint32_t)(bal >> 32);
  }
  __syncthreads();
  int tc = tieCnt < 256 ? tieCnt : 256;
  if (t < tc) {
    int s = tielist[t];
    uint32_t rank = 0;
    for (int j = 0; j < tc; ++j) rank += (tielist[j] < s) ? 1u : 0u;
    if (rank < need) {
      const bool ours = (h == 0) ? (s < SEQ / 2) : (s >= SEQ / 2);
      if (ours) {
        float c0v = rowf[(size_t)s * 6];
        if (!(c0v != c0v)) atomicOr(&fm[s >> 5], 1u << (s & 31));
      }
    }
  }
  __syncthreads();

  // ---------------- copy tail: pure select + plain store ----------------
  {
    const float t0 = tok[0], t1 = tok[1], t2 = tok[2];
    const float t3 = tok[3], t4 = tok[4], t5 = tok[5];
    f32x4* ro4 = (f32x4*)out + rowBase4;
    const int qbase = h * HALF4;        // f4 index within row

    // issue the remaining 4 loads first (in flight under the first 8 stores)
    f32x4 b8  = rf4[t + 8192];
    f32x4 b9  = rf4[t + 9216];
    f32x4 b10 = rf4[t + 10240];
    f32x4 b11 = rf4[t + 11264];

    ro4[t]         = tok_select(s0, qbase + t,         fm, t0, t1, t2, t3, t4, t5);
    ro4[t + 1024]  = tok_select(s1, qbase + t + 1024,  fm, t0, t1, t2, t3, t4, t5);
    ro4[t + 2048]  = tok_select(s2, qbase + t + 2048,  fm, t0, t1, t2, t3, t4, t5);
    ro4[t + 3072]  = tok_select(s3, qbase + t + 3072,  fm, t0, t1, t2, t3, t4, t5);
    ro4[t + 4096]  = tok_select(s4, qbase + t + 4096,  fm, t0, t1, t2, t3, t4, t5);
    ro4[t + 5120]  = tok_select(s5, qbase + t + 5120,  fm, t0, t1, t2, t3, t4, t5);
    ro4[t + 6144]  = tok_select(s6, qbase + t + 6144,  fm, t0, t1, t2, t3, t4, t5);
    ro4[t + 7168]  = tok_select(s7, qbase + t + 7168,  fm, t0, t1, t2, t3, t4, t5);
    ro4[t + 8192]  = tok_select(b8,  qbase + t + 8192,  fm, t0, t1, t2, t3, t4, t5);
    ro4[t + 9216]  = tok_select(b9,  qbase + t + 9216,  fm, t0, t1, t2, t3, t4, t5);
    ro4[t + 10240] = tok_select(b10, qbase + t + 10240, fm, t0, t1, t2, t3, t4, t5);
    ro4[t + 11264] = tok_select(b11, qbase + t + 11264, fm, t0, t1, t2, t3, t4, t5);
  }
}

extern "C" void kernel_launch(void* const* d_in, const int* in_sizes, int n_in,
                              void* d_out, int out_size, void* d_ws, size_t ws_size,
                              hipStream_t stream) {
  const float* feat = (const float*)d_in[0];
  const float* tok = (const float*)d_in[1];
  float* out = (float*)d_out;

  // ---- host-side key derivation (partitionable threefry) ----
  // key(1234) -> (0, 1234); split(key,3) foldlike: child i = tf(key, (0, i))
  uint32_t klen0, klen1, kst0, kst1, kn0, kn1;
  tf2x32(0u, 1234u, 0u, 0u, klen0, klen1);   // k_len
  tf2x32(0u, 1234u, 0u, 1u, kst0, kst1);     // k_start
  tf2x32(0u, 1234u, 0u, 2u, kn0, kn1);       // k_noise
  uint32_t lh0, lh1, ll0, ll1;
  tf2x32(klen0, klen1, 0u, 0u, lh0, lh1);    // unused (span=16 pow2)
  tf2x32(klen0, klen1, 0u, 1u, ll0, ll1);
  (void)lh0; (void)lh1;
  uint32_t sh0, sh1, sl0, sl1;
  tf2x32(kst0, kst1, 0u, 0u, sh0, sh1);
  tf2x32(kst0, kst1, 0u, 1u, sl0, sl1);
  Keys K{ ll0, ll1, sh0, sh1, sl0, sl1, kn0, kn1 };

  // Single ordinary launch: 2 blocks per row, no workspace dependency.
  hipLaunchKernelGGL(rowpair_kernel, dim3(2 * NB), dim3(1024), 0, stream,
                     feat, tok, out, K);
}

// Round 6
// 114.619 us; speedup vs baseline: 1.0344x; 1.0344x over previous
//
#include <hip/hip_runtime.h>
#include <stdint.h>

// Problem constants (from reference):
//   features: [128, 16384, 6] f32; mask_token: [6] f32; seed 1234
//   MASK_RATIO=0.15 -> target_masked = int(16384*0.15) = 2457
//   n_spans = max(1, int(2457/12.5*2)) = 393
constexpr int NB = 128;
constexpr int SEQ = 16384;
constexpr int NSPANS = 393;
constexpr uint32_t TGT = 2457u;
constexpr int ROWF = SEQ * 6;           // 98304 floats per row
constexpr int ROWF4 = ROWF / 4;         // 24576 float4 per row
constexpr int HALF4 = ROWF4 / 2;        // 12288 float4 per half-row

typedef float f32x4 __attribute__((ext_vector_type(4)));

struct Keys {
  uint32_t klo0, klo1;     // randint(k_len) child-2 key (span=16 pow2: only lower bits matter)
  uint32_t khi_s0, khi_s1; // randint(k_start) child-1 key -> higher bits
  uint32_t klo_s0, klo_s1; // randint(k_start) child-2 key -> lower bits
  uint32_t kn0, kn1;       // k_noise
};

// JAX threefry2x32 (20 rounds)
__host__ __device__ inline void tf2x32(uint32_t k0, uint32_t k1,
                                       uint32_t x0, uint32_t x1,
                                       uint32_t& o0, uint32_t& o1) {
  uint32_t ks[3] = {k0, k1, k0 ^ k1 ^ 0x1BD11BDAu};
  uint32_t a = x0 + ks[0], b = x1 + ks[1];
  const uint32_t rot[2][4] = {{13u,15u,26u,6u},{17u,29u,16u,24u}};
#pragma unroll
  for (int i = 0; i < 5; ++i) {
    const uint32_t* r = rot[i & 1];
#pragma unroll
    for (int j = 0; j < 4; ++j) {
      a += b;
      b = (b << r[j]) | (b >> (32u - r[j]));
      b ^= a;
    }
    a += ks[(i + 1) % 3];
    b += ks[(i + 2) % 3] + (uint32_t)(i + 1);
  }
  o0 = a; o1 = b;
}

// JAX partitionable random_bits (32-bit): bits[j] = a ^ b, (a,b) = tf(key, (0, j))
__device__ inline uint32_t rbits(uint32_t k0, uint32_t k1, uint32_t j) {
  uint32_t o0, o1;
  tf2x32(k0, k1, 0u, j, o0, o1);
  return o0 ^ o1;
}

// LDS-only barrier: per-thread drain of DS/SMEM ops, then raw s_barrier.
// Does NOT wait vmcnt -> global copy loads/stores stay in flight across all
// maskgen phases (the __syncthreads vmcnt(0) drain was R4's serialization).
// Pattern is the m201 8-phase template's (field-proven in plain HIP).
__device__ inline void bar_lds() {
  asm volatile("s_waitcnt lgkmcnt(0)" ::: "memory");
  __builtin_amdgcn_s_barrier();
}

// =============== R13: R12 with the scatter-fix OOB bug fixed ===============
// R12 crashed: scatter-fix word index was h*512+t/2 (half-row is 256 fm
// words, not 512) -> LDS OOB read + global OOB write for h==1 -> HSA fault.
// Single-line fix: wi = h*256 + t/2. Everything else unchanged so the R12
// experiment (copy-first + lgkm-only barriers) actually gets measured.
//
// 256 blocks x 1024 threads (1 block/CU). Block bid: row b = bid>>1, half
// h = bid&1. Schedule per block:
//   1. streaming copy of own half-row (12 f32x4, pipelined) -- stores retire
//      at L2 and write back to HBM asynchronously UNDER maskgen
//   2. redundant maskgen (R7-validated phases, verbatim) with lgkm-only
//      barriers so the copy traffic is never drained at a barrier
//   3. one __syncthreads (vmcnt drain: copy stores visible to own block)
//   4. scatter-fix: rewrite masked+valid positions of own half with token
//      (validity probed here; reference semantics: tie ranking ignores
//      validity, emission respects it -- copy already wrote originals)
__global__ __launch_bounds__(1024, 4)
void rowpair_kernel(const float* __restrict__ feat, const float* __restrict__ tok,
                    float* __restrict__ out, Keys K) {
  __shared__ uint32_t hist[4096];      // 16 KB
  __shared__ uint32_t cov[SEQ / 32];   // 2 KB
  __shared__ uint32_t fm[SEQ / 32];    // 2 KB
  __shared__ uint32_t wsum[16], ssum[16];
  __shared__ int tielist[256];
  __shared__ uint32_t sH, sA, sT, sN;
  __shared__ int tieCnt;

  const int t = threadIdx.x;
  const int lane = t & 63;
  const int wid = t >> 6;
  const uint32_t bid = blockIdx.x;
  const uint32_t b = bid >> 1;         // row
  const int h = (int)(bid & 1u);       // half

  const size_t rowBase4 = (size_t)b * ROWF4 + (size_t)h * HALF4;
  const f32x4* rf4 = (const f32x4*)feat + rowBase4;
  f32x4* ro4 = (f32x4*)out + rowBase4;

  // ---- 1. streaming copy, pipelined (max 8 f32x4 = 32 VGPR live) ----
  {
    f32x4 v0 = rf4[t];
    f32x4 v1 = rf4[t + 1024];
    f32x4 v2 = rf4[t + 2048];
    f32x4 v3 = rf4[t + 3072];
    f32x4 v4 = rf4[t + 4096];
    f32x4 v5 = rf4[t + 5120];
    f32x4 v6 = rf4[t + 6144];
    f32x4 v7 = rf4[t + 7168];
    ro4[t]        = v0;
    ro4[t + 1024] = v1;
    ro4[t + 2048] = v2;
    ro4[t + 3072] = v3;
    f32x4 v8  = rf4[t + 8192];
    f32x4 v9  = rf4[t + 9216];
    f32x4 v10 = rf4[t + 10240];
    f32x4 v11 = rf4[t + 11264];
    ro4[t + 4096] = v4;
    ro4[t + 5120] = v5;
    ro4[t + 6144] = v6;
    ro4[t + 7168] = v7;
    ro4[t + 8192]  = v8;
    ro4[t + 9216]  = v9;
    ro4[t + 10240] = v10;
    ro4[t + 11264] = v11;
  }

  // ---- 2. maskgen (R7-validated algorithm; lgkm-only barriers) ----
  for (int i = t; i < 4096; i += 1024) hist[i] = 0u;
  if (t < SEQ / 32) cov[t] = 0u;
  if (t == 0) tieCnt = 0;
  bar_lds();

  // ---- phase 1: spans (one thread per span, LDS atomicOr) ----
  if (t < NSPANS) {
    uint32_t j = b * (uint32_t)NSPANS + (uint32_t)t;
    uint32_t lenb = rbits(K.klo0, K.klo1, j);
    uint32_t len = 5u + (lenb & 15u);
    uint32_t hb = rbits(K.khi_s0, K.khi_s1, j);
    uint32_t lb = rbits(K.klo_s0, K.klo_s1, j);
    const uint32_t span = 16379u;       // 2^32 % 16379 = 400
    uint32_t start = ((hb % span) * 400u + (lb % span)) % span;
    uint32_t end = start + len; if (end > (uint32_t)SEQ) end = SEQ;
    uint32_t w0 = start >> 5, w1 = (end - 1u) >> 5;
    for (uint32_t w = w0; w <= w1; ++w) {
      uint32_t bs = (w == w0) ? (start & 31u) : 0u;
      uint32_t be = (w == w1) ? ((end - 1u) & 31u) : 31u;
      uint32_t n = be - bs + 1u;
      uint32_t m = (n >= 32u) ? 0xFFFFFFFFu : (((1u << n) - 1u) << bs);
      atomicOr(&cov[w], m);
    }
  }
  bar_lds();

  // ---- phase 2: threefry pass -> scores in registers + level-1 hist ----
  // All sr[]-touching loops fully unrolled (runtime-indexed regs -> scratch, rule #20).
  const uint32_t jb = b << 14;
  uint32_t sr[16];
#pragma unroll
  for (int i = 0; i < 16; ++i) {
    int s = (i << 10) + t;
    uint32_t bits = rbits(K.kn0, K.kn1, jb + (uint32_t)s);
    uint32_t si = (bits >> 9) + (((cov[s >> 5] >> (s & 31)) & 1u) << 23);
    sr[i] = si;
    atomicAdd(&hist[si >> 12], 1u);
  }
  bar_lds();

  // ---- phase 3: level-1 select via wave-shuffle suffix scan ----
  {
    uint32_t mysum = 0;
#pragma unroll
    for (int i = 0; i < 4; ++i) mysum += hist[t * 4 + i];
    uint32_t v = mysum;
#pragma unroll
    for (int off = 1; off < 64; off <<= 1) {
      uint32_t n = __shfl_down(v, off, 64);
      if (lane + off < 64) v += n;
    }
    if (lane == 0) wsum[wid] = v;   // wave totals
    bar_lds();
    if (t < 16) {
      uint32_t w = wsum[t];
#pragma unroll
      for (int off = 1; off < 16; off <<= 1) {
        uint32_t n = __shfl_down(w, off, 64);
        if (t + off < 16) w += n;
      }
      ssum[t] = w;                  // inclusive suffix over wave totals
    }
    bar_lds();
    uint32_t mine = v + (ssum[wid] - wsum[wid]);   // sum of chunks >= mine
    uint32_t above = mine - mysum;                  // strictly above my chunk
    if (above < TGT && TGT <= mine) {
      uint32_t run = above;
      for (int hb = t * 4 + 3; hb >= t * 4; --hb) {
        uint32_t c = hist[hb];
        if (run + c >= TGT) { sH = (uint32_t)hb; sA = run; break; }
        run += c;
      }
    }
  }
  bar_lds();
  uint32_t H = sH;
  uint32_t targetB = TGT - sA;

  for (int i = t; i < 4096; i += 1024) hist[i] = 0u;
  bar_lds();

  // ---- phase 4: level-2 histogram from registers ----
#pragma unroll
  for (int i = 0; i < 16; ++i) {
    uint32_t si = sr[i];
    if ((si >> 12) == H) atomicAdd(&hist[si & 4095u], 1u);
  }
  bar_lds();
  {
    uint32_t mysum = 0;
#pragma unroll
    for (int i = 0; i < 4; ++i) mysum += hist[t * 4 + i];
    uint32_t v = mysum;
#pragma unroll
    for (int off = 1; off < 64; off <<= 1) {
      uint32_t n = __shfl_down(v, off, 64);
      if (lane + off < 64) v += n;
    }
    if (lane == 0) wsum[wid] = v;
    bar_lds();
    if (t < 16) {
      uint32_t w = wsum[t];
#pragma unroll
      for (int off = 1; off < 16; off <<= 1) {
        uint32_t n = __shfl_down(w, off, 64);
        if (t + off < 16) w += n;
      }
      ssum[t] = w;
    }
    bar_lds();
    uint32_t mine = v + (ssum[wid] - wsum[wid]);
    uint32_t above = mine - mysum;
    if (above < targetB && targetB <= mine) {
      uint32_t run = above;
      for (int lb = t * 4 + 3; lb >= t * 4; --lb) {
        uint32_t c = hist[lb];
        if (run + c >= targetB) {
          sT = (H << 12) | (uint32_t)lb;
          sN = targetB - run;   // # ties at T accepted (lowest indices first)
          break;
        }
        run += c;
      }
    }
  }
  bar_lds();
  uint32_t T = sT, need = sN;

  // ---- phase 5: emit bits via ballot; rank ties by index (validated form) ----
#pragma unroll
  for (int i = 0; i < 16; ++i) {
    int s = (i << 10) + t;
    uint32_t si = sr[i];
    unsigned long long bal = __ballot(si > T);
    if (si == T) {
      int idx = atomicAdd(&tieCnt, 1);
      if (idx < 256) tielist[idx] = s;
    }
    if (lane == 0)       fm[s >> 5] = (uint32_t)bal;
    else if (lane == 32) fm[s >> 5] = (uint32_t)(bal >> 32);
  }
  bar_lds();
  int tc = tieCnt < 256 ? tieCnt : 256;
  if (t < tc) {
    int s = tielist[t];
    uint32_t rank = 0;
    for (int j = 0; j < tc; ++j) rank += (tielist[j] < s) ? 1u : 0u;
    if (rank < need) atomicOr(&fm[s >> 5], 1u << (s & 31));
  }

  // ---- 3. full barrier: fm final (lgkm) AND copy stores visible (vmcnt) ----
  __syncthreads();

  // ---- 4. scatter-fix own half: masked & valid positions get the token ----
  // 512 threads, one per 16-bit halfword of our half's 256 fm words
  // (half-row = 8192 positions = 256 words; R12's h*512 was the OOB bug).
  if (t < 512) {
    const int wi = h * 256 + (t >> 1);               // fm word index, 0..511
    const uint32_t w = fm[wi];
    const uint32_t hw = (w >> ((t & 1) << 4)) & 0xFFFFu;
    if (hw) {
      const float2 t01 = make_float2(tok[0], tok[1]);
      const float2 t23 = make_float2(tok[2], tok[3]);
      const float2 t45 = make_float2(tok[4], tok[5]);
      uint32_t hbits = hw;
      const size_t basePos = (size_t)b * SEQ + (size_t)wi * 32 + (size_t)((t & 1) << 4);
      while (hbits) {
        int bit = __ffs(hbits) - 1;
        hbits &= hbits - 1u;
        size_t p = basePos + (size_t)bit;
        float c0 = feat[p * 6];
        if (!(c0 != c0)) {                        // valid = !isnan(channel 0)
          float2* o = (float2*)(out + p * 6);     // 24B, always 8B-aligned
          o[0] = t01; o[1] = t23; o[2] = t45;
        }
      }
    }
  }
}

extern "C" void kernel_launch(void* const* d_in, const int* in_sizes, int n_in,
                              void* d_out, int out_size, void* d_ws, size_t ws_size,
                              hipStream_t stream) {
  const float* feat = (const float*)d_in[0];
  const float* tok = (const float*)d_in[1];
  float* out = (float*)d_out;

  // ---- host-side key derivation (partitionable threefry) ----
  // key(1234) -> (0, 1234); split(key,3) foldlike: child i = tf(key, (0, i))
  uint32_t klen0, klen1, kst0, kst1, kn0, kn1;
  tf2x32(0u, 1234u, 0u, 0u, klen0, klen1);   // k_len
  tf2x32(0u, 1234u, 0u, 1u, kst0, kst1);     // k_start
  tf2x32(0u, 1234u, 0u, 2u, kn0, kn1);       // k_noise
  uint32_t lh0, lh1, ll0, ll1;
  tf2x32(klen0, klen1, 0u, 0u, lh0, lh1);    // unused (span=16 pow2)
  tf2x32(klen0, klen1, 0u, 1u, ll0, ll1);
  (void)lh0; (void)lh1;
  uint32_t sh0, sh1, sl0, sl1;
  tf2x32(kst0, kst1, 0u, 0u, sh0, sh1);
  tf2x32(kst0, kst1, 0u, 1u, sl0, sl1);
  Keys K{ ll0, ll1, sh0, sh1, sl0, sl1, kn0, kn1 };

  // Single ordinary launch: 2 blocks per row, no workspace dependency.
  hipLaunchKernelGGL(rowpair_kernel, dim3(2 * NB), dim3(1024), 0, stream,
                     feat, tok, out, K);
}

// Round 9
// 111.057 us; speedup vs baseline: 1.0676x; 1.0321x over previous
//
#include <hip/hip_runtime.h>
#include <stdint.h>

// Problem constants (from reference):
//   features: [128, 16384, 6] f32; mask_token: [6] f32; seed 1234
//   MASK_RATIO=0.15 -> target_masked = int(16384*0.15) = 2457
//   n_spans = max(1, int(2457/12.5*2)) = 393
constexpr int NB = 128;
constexpr int SEQ = 16384;
constexpr int NF = 6;
constexpr int NSPANS = 393;
constexpr uint32_t TGT = 2457u;
constexpr int ROWF = SEQ * NF;          // 98304 floats per row
constexpr int ROWF4 = ROWF / 4;         // 24576 float4 per row
constexpr int TOT4 = NB * ROWF4;        // 3145728 float4 total
constexpr int COPY_PT = 8;              // f4 per thread in copy blocks
constexpr int COPY_BLOCKS = TOT4 / (COPY_PT * 1024);   // 384

// ---- workspace layout (dword offsets) ----
constexpr int FM_OFF = 0;                           // 128*512 final mask bits
constexpr int FM_DW = NB * (SEQ / 32);              // 65536
constexpr size_t WS_BYTES = (size_t)FM_DW * 4;      // 256 KB

typedef float f32x4 __attribute__((ext_vector_type(4)));

struct Keys {
  uint32_t klo0, klo1;     // randint(k_len) child-2 key (span=16 pow2: only lower bits matter)
  uint32_t khi_s0, khi_s1; // randint(k_start) child-1 key -> higher bits
  uint32_t klo_s0, klo_s1; // randint(k_start) child-2 key -> lower bits
  uint32_t kn0, kn1;       // k_noise
};

// JAX threefry2x32 (20 rounds)
__host__ __device__ inline void tf2x32(uint32_t k0, uint32_t k1,
                                       uint32_t x0, uint32_t x1,
                                       uint32_t& o0, uint32_t& o1) {
  uint32_t ks[3] = {k0, k1, k0 ^ k1 ^ 0x1BD11BDAu};
  uint32_t a = x0 + ks[0], b = x1 + ks[1];
  const uint32_t rot[2][4] = {{13u,15u,26u,6u},{17u,29u,16u,24u}};
#pragma unroll
  for (int i = 0; i < 5; ++i) {
    const uint32_t* r = rot[i & 1];
#pragma unroll
    for (int j = 0; j < 4; ++j) {
      a += b;
      b = (b << r[j]) | (b >> (32u - r[j]));
      b ^= a;
    }
    a += ks[(i + 1) % 3];
    b += ks[(i + 2) % 3] + (uint32_t)(i + 1);
  }
  o0 = a; o1 = b;
}

// JAX partitionable random_bits (32-bit): bits[j] = a ^ b, (a,b) = tf(key, (0, j))
__device__ inline uint32_t rbits(uint32_t k0, uint32_t k1, uint32_t j) {
  uint32_t o0, o1;
  tf2x32(k0, k1, 0u, j, o0, o1);
  return o0 ^ o1;
}

// =============== R16: R14 with the asm staging fence replaced ===============
// R7/R8 both died at container level with the SAME kernel whose only novel
// construct was an inline-asm fence with 8x 128-bit "v" operands (suspected
// backend ICE). Same intent, hardened construct: sched_barrier(0) pins all 8
// loads before the stores at compile time (rule #18/T19 builtin, field-proven
// on gfx950). Everything else identical to R14:
// R0 two-kernel structure (best measured, 112.1) + high-MLP copy path
// (8 f4/thread; all prior fused variants trickled at ~2 loads outstanding).
__global__ __launch_bounds__(1024)
void fused_kernel(const float* __restrict__ feat, float* __restrict__ out,
                  uint32_t* __restrict__ ws, Keys K) {
  __shared__ uint32_t hist[4096];      // 16 KB
  __shared__ uint32_t cov[SEQ / 32];   // 2 KB
  __shared__ uint32_t fm[SEQ / 32];    // 2 KB
  __shared__ uint32_t wsum[16], ssum[16];
  __shared__ int tielist[256];
  __shared__ uint32_t sH, sA, sT, sN;
  __shared__ int tieCnt;

  const int t = threadIdx.x;

  if (blockIdx.x >= (unsigned)NB) {
    // ---------------- copy path: 8 f4/thread, loads pinned before stores ----------------
    const uint32_t n = blockIdx.x - NB;          // 0..383
    const f32x4* f4 = (const f32x4*)feat + (size_t)n * (COPY_PT * 1024);
    f32x4* o4 = (f32x4*)out + (size_t)n * (COPY_PT * 1024);
    f32x4 v0 = f4[t];
    f32x4 v1 = f4[t + 1024];
    f32x4 v2 = f4[t + 2048];
    f32x4 v3 = f4[t + 3072];
    f32x4 v4 = f4[t + 4096];
    f32x4 v5 = f4[t + 5120];
    f32x4 v6 = f4[t + 6144];
    f32x4 v7 = f4[t + 7168];
    // Compile-time scheduling fence: no instruction may cross -> all 8
    // global_load_dwordx4 issue before the first store (per-wave MLP = 8).
    __builtin_amdgcn_sched_barrier(0);
    o4[t]        = v0;
    o4[t + 1024] = v1;
    o4[t + 2048] = v2;
    o4[t + 3072] = v3;
    o4[t + 4096] = v4;
    o4[t + 5120] = v5;
    o4[t + 6144] = v6;
    o4[t + 7168] = v7;
    return;
  }

  // ---------------- maskgen path (R0/R7-validated, scores in 16 VGPRs) ----------------
  const int lane = t & 63;
  const int wid = t >> 6;
  const uint32_t b = blockIdx.x;

  for (int i = t; i < 4096; i += 1024) hist[i] = 0u;
  if (t < SEQ / 32) cov[t] = 0u;
  if (t == 0) tieCnt = 0;
  __syncthreads();

  // ---- phase 1: spans (one thread per span, LDS atomicOr) ----
  if (t < NSPANS) {
    uint32_t j = b * (uint32_t)NSPANS + (uint32_t)t;
    uint32_t lenb = rbits(K.klo0, K.klo1, j);
    uint32_t len = 5u + (lenb & 15u);
    uint32_t hb = rbits(K.khi_s0, K.khi_s1, j);
    uint32_t lb = rbits(K.klo_s0, K.klo_s1, j);
    const uint32_t span = 16379u;       // 2^32 % 16379 = 400
    uint32_t start = ((hb % span) * 400u + (lb % span)) % span;
    uint32_t end = start + len; if (end > (uint32_t)SEQ) end = SEQ;
    uint32_t w0 = start >> 5, w1 = (end - 1u) >> 5;
    for (uint32_t w = w0; w <= w1; ++w) {
      uint32_t bs = (w == w0) ? (start & 31u) : 0u;
      uint32_t be = (w == w1) ? ((end - 1u) & 31u) : 31u;
      uint32_t n = be - bs + 1u;
      uint32_t m = (n >= 32u) ? 0xFFFFFFFFu : (((1u << n) - 1u) << bs);
      atomicOr(&cov[w], m);
    }
  }
  __syncthreads();

  // ---- phase 2: single threefry pass -> scores in registers + level-1 hist ----
  const uint32_t jb = b << 14;
  uint32_t sr[16];
#pragma unroll
  for (int i = 0; i < 16; ++i) {
    int s = (i << 10) + t;
    uint32_t bits = rbits(K.kn0, K.kn1, jb + (uint32_t)s);
    uint32_t si = (bits >> 9) + (((cov[s >> 5] >> (s & 31)) & 1u) << 23);
    sr[i] = si;
    atomicAdd(&hist[si >> 12], 1u);
  }
  __syncthreads();

  // ---- phase 3: level-1 select via wave-shuffle suffix scan (4 bins/thread) ----
  {
    uint32_t mysum = 0;
#pragma unroll
    for (int i = 0; i < 4; ++i) mysum += hist[t * 4 + i];
    uint32_t v = mysum;
#pragma unroll
    for (int off = 1; off < 64; off <<= 1) {
      uint32_t n = __shfl_down(v, off, 64);
      if (lane + off < 64) v += n;
    }
    if (lane == 0) wsum[wid] = v;   // wave totals
    __syncthreads();
    if (t < 16) {
      uint32_t w = wsum[t];
#pragma unroll
      for (int off = 1; off < 16; off <<= 1) {
        uint32_t n = __shfl_down(w, off, 64);
        if (t + off < 16) w += n;
      }
      ssum[t] = w;                  // inclusive suffix over wave totals
    }
    __syncthreads();
    uint32_t mine = v + (ssum[wid] - wsum[wid]);   // sum of chunks >= mine
    uint32_t above = mine - mysum;                  // strictly above my chunk
    if (above < TGT && TGT <= mine) {
      uint32_t run = above;
      for (int hb = t * 4 + 3; hb >= t * 4; --hb) {
        uint32_t c = hist[hb];
        if (run + c >= TGT) { sH = (uint32_t)hb; sA = run; break; }
        run += c;
      }
    }
  }
  __syncthreads();
  uint32_t H = sH;
  uint32_t targetB = TGT - sA;

  for (int i = t; i < 4096; i += 1024) hist[i] = 0u;
  __syncthreads();

  // ---- phase 4: level-2 histogram from registers ----
#pragma unroll
  for (int i = 0; i < 16; ++i) {
    uint32_t si = sr[i];
    if ((si >> 12) == H) atomicAdd(&hist[si & 4095u], 1u);
  }
  __syncthreads();
  {
    uint32_t mysum = 0;
#pragma unroll
    for (int i = 0; i < 4; ++i) mysum += hist[t * 4 + i];
    uint32_t v = mysum;
#pragma unroll
    for (int off = 1; off < 64; off <<= 1) {
      uint32_t n = __shfl_down(v, off, 64);
      if (lane + off < 64) v += n;
    }
    if (lane == 0) wsum[wid] = v;
    __syncthreads();
    if (t < 16) {
      uint32_t w = wsum[t];
#pragma unroll
      for (int off = 1; off < 16; off <<= 1) {
        uint32_t n = __shfl_down(w, off, 64);
        if (t + off < 16) w += n;
      }
      ssum[t] = w;
    }
    __syncthreads();
    uint32_t mine = v + (ssum[wid] - wsum[wid]);
    uint32_t above = mine - mysum;
    if (above < targetB && targetB <= mine) {
      uint32_t run = above;
      for (int lb = t * 4 + 3; lb >= t * 4; --lb) {
        uint32_t c = hist[lb];
        if (run + c >= targetB) {
          sT = (H << 12) | (uint32_t)lb;
          sN = targetB - run;   // # ties at T accepted (lowest indices first)
          break;
        }
        run += c;
      }
    }
  }
  __syncthreads();
  uint32_t T = sT, need = sN;

  // ---- phase 5: emit bits via ballot from registers; rank ties by index ----
#pragma unroll
  for (int i = 0; i < 16; ++i) {
    int s = (i << 10) + t;
    uint32_t si = sr[i];
    unsigned long long bal = __ballot(si > T);
    if (si == T) {
      int idx = atomicAdd(&tieCnt, 1);
      if (idx < 256) tielist[idx] = s;
    }
    if (lane == 0)       fm[s >> 5] = (uint32_t)bal;
    else if (lane == 32) fm[s >> 5] = (uint32_t)(bal >> 32);
  }
  __syncthreads();
  int tc = tieCnt < 256 ? tieCnt : 256;
  if (t < tc) {
    int s = tielist[t];
    uint32_t rank = 0;
    for (int j = 0; j < tc; ++j) rank += (tielist[j] < s) ? 1u : 0u;
    if (rank < need) atomicOr(&fm[s >> 5], 1u << (s & 31));
  }
  __syncthreads();
  if (t < SEQ / 32) ws[FM_OFF + (b << 9) + t] = fm[t];
}

// =============== fixup: rewrite masked+valid positions with the token ===============
// One thread per 16-bit halfword (131072 threads, 512 blocks; R1-validated).
// Token stores as 3x float2 (24 B always 8-B aligned).
__global__ __launch_bounds__(256)
void fixup_kernel(const float* __restrict__ feat, const float* __restrict__ tok,
                  const uint32_t* __restrict__ ws, float* __restrict__ out) {
  int g = blockIdx.x * 256 + threadIdx.x;       // halfword index, 0..131071
  uint32_t w = ws[FM_OFF + (g >> 1)];
  uint32_t h = (w >> ((g & 1) << 4)) & 0xFFFFu;
  if (!h) return;
  float2 t01 = make_float2(tok[0], tok[1]);
  float2 t23 = make_float2(tok[2], tok[3]);
  float2 t45 = make_float2(tok[4], tok[5]);
  size_t basePos = (size_t)g * 16;
  while (h) {
    int bit = __ffs(h) - 1;
    h &= h - 1u;
    size_t p = basePos + (size_t)bit;
    float c0 = feat[p * 6];
    if (!(c0 != c0)) {                          // valid = !isnan(channel 0)
      float2* o = (float2*)(out + p * 6);
      o[0] = t01; o[1] = t23; o[2] = t45;
    }
  }
}

// =============== fallback: fully fused single kernel (validated round 2) ===============

__device__ inline uint32_t score_int(const Keys& K, uint32_t b, int s,
                                     const uint32_t* cov) {
  uint32_t j = b * (uint32_t)SEQ + (uint32_t)s;
  uint32_t bits = rbits(K.kn0, K.kn1, j);
  return (bits >> 9) + (((cov[s >> 5] >> (s & 31)) & 1u) << 23);
}

__global__ __launch_bounds__(256)
void mask_kernel(const float* __restrict__ feat, const float* __restrict__ tok,
                 float* __restrict__ out, Keys K) {
  __shared__ uint32_t cov[SEQ / 32];
  __shared__ uint32_t fm[SEQ / 32];
  __shared__ uint32_t hist[4096];
  __shared__ uint32_t part[256];
  __shared__ uint32_t sH, sA, sT, sN;

  const int t = threadIdx.x;
  const uint32_t b = blockIdx.x;

  for (int i = t; i < 4096; i += 256) hist[i] = 0u;
  for (int i = t; i < SEQ / 32; i += 256) cov[i] = 0u;
  __syncthreads();

  for (int i = t; i < NSPANS; i += 256) {
    uint32_t j = b * (uint32_t)NSPANS + (uint32_t)i;
    uint32_t lenb = rbits(K.klo0, K.klo1, j);
    uint32_t len = 5u + (lenb & 15u);
    uint32_t hb = rbits(K.khi_s0, K.khi_s1, j);
    uint32_t lb = rbits(K.klo_s0, K.klo_s1, j);
    const uint32_t span = 16379u;
    uint32_t start = ((hb % span) * 400u + (lb % span)) % span;
    uint32_t end = start + len; if (end > (uint32_t)SEQ) end = SEQ;
    uint32_t w0 = start >> 5, w1 = (end - 1u) >> 5;
    for (uint32_t w = w0; w <= w1; ++w) {
      uint32_t bs = (w == w0) ? (start & 31u) : 0u;
      uint32_t be = (w == w1) ? ((end - 1u) & 31u) : 31u;
      uint32_t n = be - bs + 1u;
      uint32_t m = (n >= 32u) ? 0xFFFFFFFFu : (((1u << n) - 1u) << bs);
      atomicOr(&cov[w], m);
    }
  }
  __syncthreads();

  for (int q = 0; q < 64; ++q) {
    uint32_t si = score_int(K, b, t + (q << 8), cov);
    atomicAdd(&hist[si >> 12], 1u);
  }
  __syncthreads();
  {
    uint32_t sum = 0;
#pragma unroll
    for (int i = 0; i < 16; ++i) sum += hist[t * 16 + i];
    part[t] = sum;
    __syncthreads();
    for (int off = 1; off < 256; off <<= 1) {
      uint32_t v = (t + off < 256) ? part[t + off] : 0u;
      __syncthreads();
      part[t] += v;
      __syncthreads();
    }
    uint32_t above = (t < 255) ? part[t + 1] : 0u;
    uint32_t mine = part[t];
    if (above < TGT && TGT <= mine) {
      uint32_t run = above;
      for (int hb = t * 16 + 15; hb >= t * 16; --hb) {
        uint32_t c = hist[hb];
        if (run + c >= TGT) { sH = (uint32_t)hb; sA = run; break; }
        run += c;
      }
    }
  }
  __syncthreads();
  uint32_t H = sH;
  uint32_t targetB = TGT - sA;

  for (int i = t; i < 4096; i += 256) hist[i] = 0u;
  __syncthreads();
  for (int q = 0; q < 64; ++q) {
    uint32_t si = score_int(K, b, t + (q << 8), cov);
    if ((si >> 12) == H) atomicAdd(&hist[si & 4095u], 1u);
  }
  __syncthreads();
  {
    uint32_t sum = 0;
#pragma unroll
    for (int i = 0; i < 16; ++i) sum += hist[t * 16 + i];
    part[t] = sum;
    __syncthreads();
    for (int off = 1; off < 256; off <<= 1) {
      uint32_t v = (t + off < 256) ? part[t + off] : 0u;
      __syncthreads();
      part[t] += v;
      __syncthreads();
    }
    uint32_t above = (t < 255) ? part[t + 1] : 0u;
    uint32_t mine = part[t];
    if (above < targetB && targetB <= mine) {
      uint32_t run = above;
      for (int lb = t * 16 + 15; lb >= t * 16; --lb) {
        uint32_t c = hist[lb];
        if (run + c >= targetB) { sT = (H << 12) | (uint32_t)lb; sN = targetB - run; break; }
        run += c;
      }
    }
  }
  __syncthreads();
  uint32_t T = sT, need = sN;

  const float* rowf = feat + (size_t)b * ROWF;
  {
    int base = t << 6;
    uint32_t cnt = 0;
    for (int i = 0; i < 64; ++i) cnt += (score_int(K, b, base + i, cov) == T) ? 1u : 0u;
    part[t] = cnt;
    __syncthreads();
    for (int off = 1; off < 256; off <<= 1) {
      uint32_t v = (t >= off) ? part[t - off] : 0u;
      __syncthreads();
      part[t] += v;
      __syncthreads();
    }
    uint32_t r = part[t] - cnt;
    uint32_t w0 = 0, w1 = 0;
    for (int i = 0; i < 64; ++i) {
      int s = base + i;
      uint32_t si = score_int(K, b, s, cov);
      bool tie = (si == T);
      bool a = (si > T) || (tie && r < need);
      r += tie ? 1u : 0u;
      float f0 = rowf[s * 6];
      a = a && !(f0 != f0);
      if (i < 32) w0 |= ((uint32_t)a) << i;
      else        w1 |= ((uint32_t)a) << (i - 32);
    }
    fm[2 * t] = w0;
    fm[2 * t + 1] = w1;
  }
  __syncthreads();

  float tk[NF];
#pragma unroll
  for (int c = 0; c < NF; ++c) tk[c] = tok[c];
  float* rowo = out + (size_t)b * ROWF;
  const float4* rf4 = (const float4*)rowf;
  float4* ro4 = (float4*)rowo;
  for (int q = t; q < ROWF4; q += 256) {
    float4 v = rf4[q];
    float vv[4] = {v.x, v.y, v.z, v.w};
    int e = q * 4;
#pragma unroll
    for (int k = 0; k < 4; ++k) {
      int ee = e + k;
      int p = ee / 6;
      int c = ee - p * 6;
      if ((fm[p >> 5] >> (p & 31)) & 1u) vv[k] = tk[c];
    }
    ro4[q] = make_float4(vv[0], vv[1], vv[2], vv[3]);
  }
}

extern "C" void kernel_launch(void* const* d_in, const int* in_sizes, int n_in,
                              void* d_out, int out_size, void* d_ws, size_t ws_size,
                              hipStream_t stream) {
  const float* feat = (const float*)d_in[0];
  const float* tok = (const float*)d_in[1];
  float* out = (float*)d_out;

  // ---- host-side key derivation (partitionable threefry) ----
  // key(1234) -> (0, 1234); split(key,3) foldlike: child i = tf(key, (0, i))
  uint32_t klen0, klen1, kst0, kst1, kn0, kn1;
  tf2x32(0u, 1234u, 0u, 0u, klen0, klen1);   // k_len
  tf2x32(0u, 1234u, 0u, 1u, kst0, kst1);     // k_start
  tf2x32(0u, 1234u, 0u, 2u, kn0, kn1);       // k_noise
  uint32_t lh0, lh1, ll0, ll1;
  tf2x32(klen0, klen1, 0u, 0u, lh0, lh1);    // unused (span=16 pow2)
  tf2x32(klen0, klen1, 0u, 1u, ll0, ll1);
  (void)lh0; (void)lh1;
  uint32_t sh0, sh1, sl0, sl1;
  tf2x32(kst0, kst1, 0u, 0u, sh0, sh1);
  tf2x32(kst0, kst1, 0u, 1u, sl0, sl1);
  Keys K{ ll0, ll1, sh0, sh1, sl0, sl1, kn0, kn1 };

  if (ws_size >= WS_BYTES) {
    uint32_t* ws = (uint32_t*)d_ws;
    hipLaunchKernelGGL(fused_kernel, dim3(NB + COPY_BLOCKS), dim3(1024), 0, stream,
                       feat, out, ws, K);
    hipLaunchKernelGGL(fixup_kernel, dim3(FM_DW * 2 / 256), dim3(256), 0, stream,
                       feat, tok, ws, out);
  } else {
    hipLaunchKernelGGL(mask_kernel, dim3(NB), dim3(256), 0, stream, feat, tok, out, K);
  }
}